// Round 16
// baseline (1108.058 us; speedup 1.0000x reference)
//
#include <hip/hip_runtime.h>
#include <cstdint>

#pragma STDC FP_CONTRACT OFF

// ---------------------------------------------------------------------------
// GridCLIP forward: hash-grid encode (16 levels x 8) -> MLP 128->256->256->1024
// Round 16: encode de-serialized. The per-corner asm-volatile value barriers
// (added in R4 paranoia) inhibit the scheduler from hoisting the next
// corner's global_load_dwordx4 pair -> up to 8 serial HBM round-trips per
// thread. Removing them is provably numerics-neutral (R1 no-barriers ==
// R4 barriers bit-identical; R5 proved pos/acc fma-invariance under the
// bf16-quantized comparison); #pragma clang fp contract(off) pins the
// arithmetic. Also: nontemporal hints on the streaming gh / out stores to
// keep the 4MB L2 for emb lines + W3 chunks. Everything else = R15.
// ---------------------------------------------------------------------------

typedef _Float16 f16;
typedef __attribute__((ext_vector_type(8))) _Float16 f16x8;
typedef __attribute__((ext_vector_type(4))) float f32x4;

#define ACT_SCALE 4096.0f
#define INV_ACT_SCALE (1.0f / 4096.0f)

__device__ __forceinline__ void gld16(const void* g, void* l) {
  __builtin_amdgcn_global_load_lds(
      (const __attribute__((address_space(1))) void*)(uintptr_t)g,
      (__attribute__((address_space(3))) void*)(uint32_t)(uintptr_t)l,
      16, 0, 0);
}

// ---------------- grid encode (XLA div->mul-reciprocal chain) --------------
__global__ __launch_bounds__(256) void grid_encode_kernel(
    const float* __restrict__ x, const float* __restrict__ emb,
    f16* __restrict__ gh, int p0, int npts)
{
#pragma clang fp contract(off)
  int g = blockIdx.x * blockDim.x + threadIdx.x;
  if (g >= npts * 16) return;
  int pl = g >> 4;
  int l  = g & 15;
  int p  = p0 + pl;

  float x0 = x[3 * p + 0];
  float x1 = x[3 * p + 1];
  float x2 = x[3 * p + 2];

  // XLA chain: t = (x+10) * 0.05f ; u = (t+1) * 0.5  (contract(off) pins
  // per-op rounding; no fusible pattern here anyway: add-then-mul)
  float t0 = (x0 + 10.0f) * 0.05f;
  float t1 = (x1 + 10.0f) * 0.05f;
  float t2 = (x2 + 10.0f) * 0.05f;
  float u0 = (t0 + 1.0f) * 0.5f;
  float u1 = (t1 + 1.0f) * 0.5f;
  float u2 = (t2 + 1.0f) * 0.5f;

  float scale = (float)((16 << l) - 1);
  // pos fma-vs-mul+add is a proven identity (R5 bit-identical)
  float pos0 = u0 * scale + 0.5f;
  float pos1 = u1 * scale + 0.5f;
  float pos2 = u2 * scale + 0.5f;

  float fb0 = floorf(pos0), fb1 = floorf(pos1), fb2 = floorf(pos2);
  float f0 = pos0 - fb0;
  float f1 = pos1 - fb1;
  float f2 = pos2 - fb2;
  uint32_t px = (uint32_t)fb0, py = (uint32_t)fb1, pz = (uint32_t)fb2;

  uint32_t mask = (l < 3) ? ((4096u << (3 * l)) - 1u) : 2097151u;
  uint32_t off;
  if (l == 0)      off = 0u;
  else if (l == 1) off = 4096u;
  else if (l == 2) off = 36864u;
  else             off = 299008u + (uint32_t)(l - 3) * 2097152u;

  float wx[2] = {1.0f - f0, f0};
  float wy[2] = {1.0f - f1, f1};
  float wz[2] = {1.0f - f2, f2};

  float acc[8];
#pragma unroll
  for (int j = 0; j < 8; ++j) acc[j] = 0.0f;

  // no asm barriers: let the scheduler hoist all 16 loads into flight
#pragma unroll
  for (int c = 0; c < 8; ++c) {
    uint32_t cx = px + (uint32_t)(c & 1);
    uint32_t cy = py + (uint32_t)((c >> 1) & 1);
    uint32_t cz = pz + (uint32_t)((c >> 2) & 1);
    float w = wx[c & 1] * wy[(c >> 1) & 1] * wz[(c >> 2) & 1];
    uint32_t h = cx ^ (cy * 2654435761u) ^ (cz * 805459861u);
    uint32_t idx = (h & mask) + off;
    const float4* e = (const float4*)(emb + (size_t)idx * 8);
    float4 e0 = e[0];
    float4 e1 = e[1];
    // contract(off): strict mul-then-add (and fma here is bf16-invisible
    // anyway — R5)
    acc[0] += w * e0.x; acc[1] += w * e0.y;
    acc[2] += w * e0.z; acc[3] += w * e0.w;
    acc[4] += w * e1.x; acc[5] += w * e1.y;
    acc[6] += w * e1.z; acc[7] += w * e1.w;
  }

  f16x8 o;
#pragma unroll
  for (int j = 0; j < 8; ++j) o[j] = (f16)(acc[j] * ACT_SCALE);
  __builtin_nontemporal_store(o, (f16x8*)&gh[(size_t)pl * 128 + l * 8]);
}

// ---------------- weight preps ---------------------------------------------
template <int K, int N>
__global__ __launch_bounds__(256) void prep_w(
    const float* __restrict__ W, f16* __restrict__ Wt)
{
  int i = blockIdx.x * 256 + threadIdx.x;
  if (i >= N * K) return;
  int n = i / K, k = i - n * K;
  Wt[i] = (f16)W[(size_t)k * N + n];
}

__global__ __launch_bounds__(256) void prep_w1f(
    const float* __restrict__ W1, f16* __restrict__ Wf1)
{
  int i = blockIdx.x * 256 + threadIdx.x;
  if (i >= 128 * 256) return;
  int e  = i & 7;
  int lr = (i >> 3) & 15;
  int kg = (i >> 7) & 15;
  int q  = i >> 11;
  int n = q * 16 + lr;
  int k = kg * 8 + e;
  Wf1[i] = (f16)W1[(size_t)k * 256 + n];
}

__global__ __launch_bounds__(256) void prep_w2f(
    const float* __restrict__ W2, f16* __restrict__ Wf2)
{
  int i = blockIdx.x * 256 + threadIdx.x;
  if (i >= 256 * 256) return;
  int e  = i & 7;
  int lr = (i >> 3) & 15;
  int kg = (i >> 7) & 31;
  int q  = i >> 12;
  int n = q * 16 + lr;
  int k = kg * 8 + e;
  Wf2[i] = (f16)W2[(size_t)k * 256 + n];
}

// ---------------- fused MLP ------------------------------------------------
__global__ __launch_bounds__(512) void fused_mlp(
    const f16* __restrict__ gh, const f16* __restrict__ Wf1,
    const float* __restrict__ b1, const f16* __restrict__ Wf2,
    const float* __restrict__ b2, const f16* __restrict__ Wt3,
    const float* __restrict__ b3, float* __restrict__ out,
    int rowBase, int nTotal)
{
  __shared__ alignas(16) f16 As2[3][4096];   // 3 x 8KB W3 chunk ring
  __shared__ alignas(16) f16 H1[128 * 256];  // 64KB swizzled h1
  __shared__ alignas(16) f16 H2[128 * 256];  // 64KB swizzled h2 (gh during ph1)
  __shared__ float B3s[1024];                // 4KB b3 cache

  const int tid  = threadIdx.x;
  const int lane = tid & 63;
  const int wid  = tid >> 6;      // 0..7
  const int bm   = blockIdx.x * 128;
  const int lr   = lane & 15;
  const int lkg  = lane >> 4;     // 0..3

  auto stage3 = [&](int buf, int c) {
    const int g   = tid;
    const int row = g >> 5;
    const int sg  = g & 31;
    const int gs  = (sg & 24) | ((sg ^ row) & 7);
    gld16(&Wt3[(size_t)(c * 16 + row) * 256 + gs * 8], &As2[buf][g * 8]);
  };

#pragma unroll
  for (int s = 0; s < 4; ++s) {
    const int g   = tid + s * 512;
    const int row = g >> 4;
    const int sg  = g & 15;
    const int gs  = (sg & 8) | ((sg ^ row) & 7);
    gld16(&gh[(size_t)(bm + row) * 128 + gs * 8], &H2[g * 8]);
  }
  stage3(0, 0);
  stage3(1, 1);
  stage3(2, 2);
  B3s[tid] = b3[tid];
  B3s[tid + 512] = b3[tid + 512];
  __syncthreads();

  // ===== phase 1 =====
  {
    const int rowg = wid >> 2, colg = wid & 3;
    f16x8 bf1[4][4];
#pragma unroll
    for (int j = 0; j < 4; ++j)
#pragma unroll
      for (int f = 0; f < 4; ++f)
        bf1[j][f] = *(const f16x8*)&Wf1[(((colg * 4 + j) * 16 + f * 4 + lkg) * 16 + lr) * 8];

    f32x4 acc[4][4];
#pragma unroll
    for (int i = 0; i < 4; ++i)
#pragma unroll
      for (int j = 0; j < 4; ++j) acc[i][j] = (f32x4){0.f, 0.f, 0.f, 0.f};

#pragma unroll
    for (int f = 0; f < 4; ++f) {
      f16x8 af[4];
#pragma unroll
      for (int i = 0; i < 4; ++i) {
        const int r  = rowg * 64 + i * 16 + lr;
        const int kg = f * 4 + lkg;
        const int gs = (kg & 8) | ((kg ^ r) & 7);
        af[i] = *(const f16x8*)&H2[r * 128 + gs * 8];
      }
#pragma unroll
      for (int i = 0; i < 4; ++i)
#pragma unroll
        for (int j = 0; j < 4; ++j)
          acc[i][j] = __builtin_amdgcn_mfma_f32_16x16x32_f16(
              af[i], bf1[j][f], acc[i][j], 0, 0, 0);
    }

#pragma unroll
    for (int i = 0; i < 4; ++i)
#pragma unroll
      for (int j = 0; j < 4; ++j) {
        const int col = colg * 64 + j * 16 + lr;
        const float bv = b1[col];
        const int kg = col >> 3, e = col & 7;
#pragma unroll
        for (int q = 0; q < 4; ++q) {
          const int row = rowg * 64 + i * 16 + lkg * 4 + q;
          const int kgs = (kg & 24) | ((kg ^ row) & 7);
          float v = fmaxf(acc[i][j][q] + bv * ACT_SCALE, 0.0f);
          H1[row * 256 + kgs * 8 + e] = (f16)v;
        }
      }
  }
  __syncthreads();

  // ===== phase 2 =====
  {
    const int rowg = wid >> 2, colg = wid & 3;
    f16x8 bf2[4][8];
#pragma unroll
    for (int j = 0; j < 4; ++j)
#pragma unroll
      for (int f = 0; f < 8; ++f)
        bf2[j][f] = *(const f16x8*)&Wf2[(((colg * 4 + j) * 32 + f * 4 + lkg) * 16 + lr) * 8];

    f32x4 acc[4][4];
#pragma unroll
    for (int i = 0; i < 4; ++i)
#pragma unroll
      for (int j = 0; j < 4; ++j) acc[i][j] = (f32x4){0.f, 0.f, 0.f, 0.f};

#pragma unroll
    for (int f = 0; f < 8; ++f) {
      f16x8 af[4];
#pragma unroll
      for (int i = 0; i < 4; ++i) {
        const int r   = rowg * 64 + i * 16 + lr;
        const int kg  = f * 4 + lkg;
        const int kgs = (kg & 24) | ((kg ^ r) & 7);
        af[i] = *(const f16x8*)&H1[r * 256 + kgs * 8];
      }
#pragma unroll
      for (int i = 0; i < 4; ++i)
#pragma unroll
        for (int j = 0; j < 4; ++j)
          acc[i][j] = __builtin_amdgcn_mfma_f32_16x16x32_f16(
              af[i], bf2[j][f], acc[i][j], 0, 0, 0);
    }

#pragma unroll
    for (int i = 0; i < 4; ++i)
#pragma unroll
      for (int j = 0; j < 4; ++j) {
        const int col = colg * 64 + j * 16 + lr;
        const float bv = b2[col];
        const int kg = col >> 3, e = col & 7;
#pragma unroll
        for (int q = 0; q < 4; ++q) {
          const int row = rowg * 64 + i * 16 + lkg * 4 + q;
          const int kgs = (kg & 24) | ((kg ^ row) & 7);
          float v = fmaxf(acc[i][j][q] + bv * ACT_SCALE, 0.0f);
          H2[row * 256 + kgs * 8 + e] = (f16)v;
        }
      }
  }
  __syncthreads();

  // ===== phase 3: counted-vmcnt streaming (T4) =====
  f16x8 af3[8];
#pragma unroll
  for (int f = 0; f < 8; ++f) {
    const int r   = wid * 16 + lr;
    const int kg  = f * 4 + lkg;
    const int kgs = (kg & 24) | ((kg ^ r) & 7);
    af3[f] = *(const f16x8*)&H2[r * 256 + kgs * 8];
  }

  auto body3 = [&](int c, int wmode, bool dostage) {
    if (wmode == 9) {
      asm volatile("s_waitcnt vmcnt(9)" ::: "memory");
      __builtin_amdgcn_sched_barrier(0);
    } else if (wmode == 8) {
      asm volatile("s_waitcnt vmcnt(8)" ::: "memory");
      __builtin_amdgcn_sched_barrier(0);
    }
    const int buf = c % 3;
    f16x8 bf3[8];
#pragma unroll
    for (int f = 0; f < 8; ++f) {
      const int kg  = f * 4 + lkg;
      const int kgs = (kg & 24) | ((kg ^ lr) & 7);
      bf3[f] = *(const f16x8*)&As2[buf][(lr * 32 + kgs) * 8];
    }
    const int col = c * 16 + lr;
    const float bv = B3s[col];
    asm volatile("s_waitcnt lgkmcnt(0)" ::: "memory");
    __builtin_amdgcn_sched_barrier(0);
    __builtin_amdgcn_s_barrier();
    __builtin_amdgcn_sched_barrier(0);
    if (dostage) stage3(buf, c + 3);
    f32x4 a = (f32x4){0.f, 0.f, 0.f, 0.f};
#pragma unroll
    for (int f = 0; f < 8; ++f)
      a = __builtin_amdgcn_mfma_f32_16x16x32_f16(af3[f], bf3[f], a, 0, 0, 0);
#pragma unroll
    for (int q = 0; q < 4; ++q) {
      const int row = bm + wid * 16 + lkg * 4 + q;
      float v = a[q] * INV_ACT_SCALE + bv;
      size_t grow = (size_t)(rowBase + row);
      float* dst = (col < 512)
                       ? (out + grow * 512 + col)
                       : (out + (size_t)nTotal * 512 + grow * 512 + (col - 512));
      __builtin_nontemporal_store(v, dst);
    }
  };

  body3(0, 0, true);
  body3(1, 0, true);
  for (int c = 2; c <= 60; ++c) body3(c, 9, true);
  body3(61, 9, false);
  body3(62, 8, false);
  body3(63, 0, false);
}

// ---------------- launch ----------------
extern "C" void kernel_launch(void* const* d_in, const int* in_sizes, int n_in,
                              void* d_out, int out_size, void* d_ws, size_t ws_size,
                              hipStream_t stream)
{
  const float* x   = (const float*)d_in[0];
  const float* emb = (const float*)d_in[1];
  const float* W1  = (const float*)d_in[2];
  const float* b1  = (const float*)d_in[3];
  const float* W2  = (const float*)d_in[4];
  const float* b2  = (const float*)d_in[5];
  const float* W3  = (const float*)d_in[6];
  const float* b3  = (const float*)d_in[7];
  float* out = (float*)d_out;

  const int NPTS = in_sizes[0] / 3;  // 262144

  f16* Wf1 = (f16*)d_ws;                 // 128*256 frag-ordered
  f16* Wf2 = Wf1 + 128 * 256;            // 256*256 frag-ordered
  f16* Wt3 = Wf2 + 256 * 256;            // 256*1024 transposed [N][K]
  f16* gh0 = Wt3 + 256 * 1024;
  const size_t wtBytes = (size_t)(128 * 256 + 256 * 256 + 256 * 1024) * sizeof(f16);

  long long cmax = (long long)((ws_size - wtBytes) / 256);
  int C = (int)((cmax / 128) * 128);
  if (C > NPTS) C = NPTS;
  if (C < 128) C = 128;

  prep_w1f<<<(128 * 256 + 255) / 256, 256, 0, stream>>>(W1, Wf1);
  prep_w2f<<<(256 * 256 + 255) / 256, 256, 0, stream>>>(W2, Wf2);
  prep_w<256, 1024><<<(256 * 1024 + 255) / 256, 256, 0, stream>>>(W3, Wt3);

  for (int p0 = 0; p0 < NPTS; p0 += C) {
    int cur = (NPTS - p0 < C) ? (NPTS - p0) : C;

    int nthr = cur * 16;
    grid_encode_kernel<<<(nthr + 255) / 256, 256, 0, stream>>>(x, emb, gh0, p0, cur);

    fused_mlp<<<cur / 128, 512, 0, stream>>>(gh0, Wf1, b1, Wf2, b2, Wt3, b3,
                                             out, p0, NPTS);
  }
}

// Round 17
// 973.914 us; speedup vs baseline: 1.1377x; 1.1377x over previous
//
#include <hip/hip_runtime.h>
#include <cstdint>

#pragma STDC FP_CONTRACT OFF

// ---------------------------------------------------------------------------
// GridCLIP forward: hash-grid encode (16 levels x 8) -> MLP 128->256->256->1024
// Round 17: encode fused INTO the MLP kernel (mega_kernel). R16 showed the
// encode at 720us / 43% HBM / VGPR=36: the compiler had serialized the corner
// gathers (2 lines in flight per thread = MLP-starved). Fix: explicit 3-pass
// encode (addresses -> 16 loads into static-indexed float4 arrays ->
// ordered accumulate), unroll-2 over tasks (32 lines in flight/thread), gh
// written straight to LDS (same swizzled layout the old prologue produced) —
// deleting gh's 64MB HBM write + 64MB read and overlapping encode gathers
// with MFMA phases GPU-wide. Phases 1-3 and all math identical to R16
// (passed) -> bit-identical output (canary absmax 4.768372e-07).
// ---------------------------------------------------------------------------

typedef _Float16 f16;
typedef __attribute__((ext_vector_type(8))) _Float16 f16x8;
typedef __attribute__((ext_vector_type(4))) float f32x4;

#define ACT_SCALE 4096.0f
#define INV_ACT_SCALE (1.0f / 4096.0f)

__device__ __forceinline__ void gld16(const void* g, void* l) {
  __builtin_amdgcn_global_load_lds(
      (const __attribute__((address_space(1))) void*)(uintptr_t)g,
      (__attribute__((address_space(3))) void*)(uint32_t)(uintptr_t)l,
      16, 0, 0);
}

// ---------------- weight preps ---------------------------------------------
template <int K, int N>
__global__ __launch_bounds__(256) void prep_w(
    const float* __restrict__ W, f16* __restrict__ Wt)
{
  int i = blockIdx.x * 256 + threadIdx.x;
  if (i >= N * K) return;
  int n = i / K, k = i - n * K;
  Wt[i] = (f16)W[(size_t)k * N + n];
}

__global__ __launch_bounds__(256) void prep_w1f(
    const float* __restrict__ W1, f16* __restrict__ Wf1)
{
  int i = blockIdx.x * 256 + threadIdx.x;
  if (i >= 128 * 256) return;
  int e  = i & 7;
  int lr = (i >> 3) & 15;
  int kg = (i >> 7) & 15;
  int q  = i >> 11;
  int n = q * 16 + lr;
  int k = kg * 8 + e;
  Wf1[i] = (f16)W1[(size_t)k * 256 + n];
}

__global__ __launch_bounds__(256) void prep_w2f(
    const float* __restrict__ W2, f16* __restrict__ Wf2)
{
  int i = blockIdx.x * 256 + threadIdx.x;
  if (i >= 256 * 256) return;
  int e  = i & 7;
  int lr = (i >> 3) & 15;
  int kg = (i >> 7) & 31;
  int q  = i >> 12;
  int n = q * 16 + lr;
  int k = kg * 8 + e;
  Wf2[i] = (f16)W2[(size_t)k * 256 + n];
}

// ---------------- mega kernel: encode + 3-layer MLP ------------------------
__global__ __launch_bounds__(512) void mega_kernel(
    const float* __restrict__ x, const float* __restrict__ emb,
    const f16* __restrict__ Wf1, const float* __restrict__ b1,
    const f16* __restrict__ Wf2, const float* __restrict__ b2,
    const f16* __restrict__ Wt3, const float* __restrict__ b3,
    float* __restrict__ out, int nTotal)
{
  __shared__ alignas(16) f16 As2[3][4096];   // 3 x 8KB W3 chunk ring
  __shared__ alignas(16) f16 H1[128 * 256];  // 64KB swizzled h1
  __shared__ alignas(16) f16 H2[128 * 256];  // 64KB swizzled h2 (gh during ph1)
  __shared__ float B3s[1024];                // 4KB b3 cache

  const int tid  = threadIdx.x;
  const int lane = tid & 63;
  const int wid  = tid >> 6;      // 0..7
  const int bm   = blockIdx.x * 128;
  const int lr   = lane & 15;
  const int lkg  = lane >> 4;     // 0..3

  auto stage3 = [&](int buf, int c) {
    const int g   = tid;
    const int row = g >> 5;
    const int sg  = g & 31;
    const int gs  = (sg & 24) | ((sg ^ row) & 7);
    gld16(&Wt3[(size_t)(c * 16 + row) * 256 + gs * 8], &As2[buf][g * 8]);
  };

  // prologue: W3 chunks 0..2 + b3 cache (drained by the post-encode barrier)
  stage3(0, 0);
  stage3(1, 1);
  stage3(2, 2);
  B3s[tid] = b3[tid];
  B3s[tid + 512] = b3[tid + 512];

  // ===== encode phase: 128 points x 16 levels -> H2 (swizzled gh layout) ===
  {
#pragma clang fp contract(off)
#pragma unroll 2
    for (int s = 0; s < 4; ++s) {
      const int t  = tid + s * 512;   // 0..2047
      const int pl = t >> 4;          // point-in-stripe 0..127
      const int l  = t & 15;          // level
      const int p  = bm + pl;

      float x0 = x[3 * p + 0];
      float x1 = x[3 * p + 1];
      float x2 = x[3 * p + 2];

      // XLA chain (R8-proven): t=(x+10)*0.05f ; u=(t+1)*0.5
      float t0 = (x0 + 10.0f) * 0.05f;
      float t1 = (x1 + 10.0f) * 0.05f;
      float t2 = (x2 + 10.0f) * 0.05f;
      float u0 = (t0 + 1.0f) * 0.5f;
      float u1 = (t1 + 1.0f) * 0.5f;
      float u2 = (t2 + 1.0f) * 0.5f;

      float scale = (float)((16 << l) - 1);
      float pos0 = u0 * scale + 0.5f;
      float pos1 = u1 * scale + 0.5f;
      float pos2 = u2 * scale + 0.5f;

      float fb0 = floorf(pos0), fb1 = floorf(pos1), fb2 = floorf(pos2);
      float f0 = pos0 - fb0;
      float f1 = pos1 - fb1;
      float f2 = pos2 - fb2;
      uint32_t px = (uint32_t)fb0, py = (uint32_t)fb1, pz = (uint32_t)fb2;

      uint32_t mask = (l < 3) ? ((4096u << (3 * l)) - 1u) : 2097151u;
      uint32_t off;
      if (l == 0)      off = 0u;
      else if (l == 1) off = 4096u;
      else if (l == 2) off = 36864u;
      else             off = 299008u + (uint32_t)(l - 3) * 2097152u;

      float wx[2] = {1.0f - f0, f0};
      float wy[2] = {1.0f - f1, f1};
      float wz[2] = {1.0f - f2, f2};

      // pass 1: all 8 corner addresses
      uint32_t idxs[8];
#pragma unroll
      for (int c = 0; c < 8; ++c) {
        uint32_t cx = px + (uint32_t)(c & 1);
        uint32_t cy = py + (uint32_t)((c >> 1) & 1);
        uint32_t cz = pz + (uint32_t)((c >> 2) & 1);
        uint32_t h = cx ^ (cy * 2654435761u) ^ (cz * 805459861u);
        idxs[c] = (h & mask) + off;
      }
      // pass 2: issue all 16 loads (static-indexed arrays -> registers)
      float4 e0[8], e1[8];
#pragma unroll
      for (int c = 0; c < 8; ++c) {
        const float4* e = (const float4*)(emb + (size_t)idxs[c] * 8);
        e0[c] = e[0];
        e1[c] = e[1];
      }
      // pass 3: ordered accumulate (identical op order to R16)
      float acc[8];
#pragma unroll
      for (int j = 0; j < 8; ++j) acc[j] = 0.0f;
#pragma unroll
      for (int c = 0; c < 8; ++c) {
        float w = wx[c & 1] * wy[(c >> 1) & 1] * wz[(c >> 2) & 1];
        acc[0] += w * e0[c].x; acc[1] += w * e0[c].y;
        acc[2] += w * e0[c].z; acc[3] += w * e0[c].w;
        acc[4] += w * e1[c].x; acc[5] += w * e1[c].y;
        acc[6] += w * e1[c].z; acc[7] += w * e1[c].w;
      }

      f16x8 o;
#pragma unroll
      for (int j = 0; j < 8; ++j) o[j] = (f16)(acc[j] * ACT_SCALE);
      // store granule l of row pl at swizzled slot (matches old gh prologue)
      const int gs = (l & 8) | ((l ^ pl) & 7);
      *(f16x8*)&H2[(pl * 16 + gs) * 8] = o;
    }
  }
  __syncthreads();  // gh visible in H2; W3 chunks 0..2 + b3 drained

  // ===== phase 1: h1 = relu(gh @ W1 + b1*S) =====
  {
    const int rowg = wid >> 2, colg = wid & 3;
    f16x8 bf1[4][4];
#pragma unroll
    for (int j = 0; j < 4; ++j)
#pragma unroll
      for (int f = 0; f < 4; ++f)
        bf1[j][f] = *(const f16x8*)&Wf1[(((colg * 4 + j) * 16 + f * 4 + lkg) * 16 + lr) * 8];

    f32x4 acc[4][4];
#pragma unroll
    for (int i = 0; i < 4; ++i)
#pragma unroll
      for (int j = 0; j < 4; ++j) acc[i][j] = (f32x4){0.f, 0.f, 0.f, 0.f};

#pragma unroll
    for (int f = 0; f < 4; ++f) {
      f16x8 af[4];
#pragma unroll
      for (int i = 0; i < 4; ++i) {
        const int r  = rowg * 64 + i * 16 + lr;
        const int kg = f * 4 + lkg;
        const int gs = (kg & 8) | ((kg ^ r) & 7);
        af[i] = *(const f16x8*)&H2[r * 128 + gs * 8];
      }
#pragma unroll
      for (int i = 0; i < 4; ++i)
#pragma unroll
        for (int j = 0; j < 4; ++j)
          acc[i][j] = __builtin_amdgcn_mfma_f32_16x16x32_f16(
              af[i], bf1[j][f], acc[i][j], 0, 0, 0);
    }

#pragma unroll
    for (int i = 0; i < 4; ++i)
#pragma unroll
      for (int j = 0; j < 4; ++j) {
        const int col = colg * 64 + j * 16 + lr;
        const float bv = b1[col];
        const int kg = col >> 3, e = col & 7;
#pragma unroll
        for (int q = 0; q < 4; ++q) {
          const int row = rowg * 64 + i * 16 + lkg * 4 + q;
          const int kgs = (kg & 24) | ((kg ^ row) & 7);
          float v = fmaxf(acc[i][j][q] + bv * ACT_SCALE, 0.0f);
          H1[row * 256 + kgs * 8 + e] = (f16)v;
        }
      }
  }
  __syncthreads();

  // ===== phase 2: h2 = relu(h1 @ W2 + b2*S) =====
  {
    const int rowg = wid >> 2, colg = wid & 3;
    f16x8 bf2[4][8];
#pragma unroll
    for (int j = 0; j < 4; ++j)
#pragma unroll
      for (int f = 0; f < 8; ++f)
        bf2[j][f] = *(const f16x8*)&Wf2[(((colg * 4 + j) * 32 + f * 4 + lkg) * 16 + lr) * 8];

    f32x4 acc[4][4];
#pragma unroll
    for (int i = 0; i < 4; ++i)
#pragma unroll
      for (int j = 0; j < 4; ++j) acc[i][j] = (f32x4){0.f, 0.f, 0.f, 0.f};

#pragma unroll
    for (int f = 0; f < 8; ++f) {
      f16x8 af[4];
#pragma unroll
      for (int i = 0; i < 4; ++i) {
        const int r   = rowg * 64 + i * 16 + lr;
        const int kg  = f * 4 + lkg;
        const int kgs = (kg & 24) | ((kg ^ r) & 7);
        af[i] = *(const f16x8*)&H1[r * 256 + kgs * 8];
      }
#pragma unroll
      for (int i = 0; i < 4; ++i)
#pragma unroll
        for (int j = 0; j < 4; ++j)
          acc[i][j] = __builtin_amdgcn_mfma_f32_16x16x32_f16(
              af[i], bf2[j][f], acc[i][j], 0, 0, 0);
    }

#pragma unroll
    for (int i = 0; i < 4; ++i)
#pragma unroll
      for (int j = 0; j < 4; ++j) {
        const int col = colg * 64 + j * 16 + lr;
        const float bv = b2[col];
        const int kg = col >> 3, e = col & 7;
#pragma unroll
        for (int q = 0; q < 4; ++q) {
          const int row = rowg * 64 + i * 16 + lkg * 4 + q;
          const int kgs = (kg & 24) | ((kg ^ row) & 7);
          float v = fmaxf(acc[i][j][q] + bv * ACT_SCALE, 0.0f);
          H2[row * 256 + kgs * 8 + e] = (f16)v;
        }
      }
  }
  __syncthreads();

  // ===== phase 3: out = h2 @ W3 + b3 — counted-vmcnt streaming (T4) =====
  f16x8 af3[8];
#pragma unroll
  for (int f = 0; f < 8; ++f) {
    const int r   = wid * 16 + lr;
    const int kg  = f * 4 + lkg;
    const int kgs = (kg & 24) | ((kg ^ r) & 7);
    af3[f] = *(const f16x8*)&H2[r * 256 + kgs * 8];
  }

  auto body3 = [&](int c, int wmode, bool dostage) {
    if (wmode == 9) {
      asm volatile("s_waitcnt vmcnt(9)" ::: "memory");
      __builtin_amdgcn_sched_barrier(0);
    } else if (wmode == 8) {
      asm volatile("s_waitcnt vmcnt(8)" ::: "memory");
      __builtin_amdgcn_sched_barrier(0);
    }
    const int buf = c % 3;
    f16x8 bf3[8];
#pragma unroll
    for (int f = 0; f < 8; ++f) {
      const int kg  = f * 4 + lkg;
      const int kgs = (kg & 24) | ((kg ^ lr) & 7);
      bf3[f] = *(const f16x8*)&As2[buf][(lr * 32 + kgs) * 8];
    }
    const int col = c * 16 + lr;
    const float bv = B3s[col];
    asm volatile("s_waitcnt lgkmcnt(0)" ::: "memory");
    __builtin_amdgcn_sched_barrier(0);
    __builtin_amdgcn_s_barrier();
    __builtin_amdgcn_sched_barrier(0);
    if (dostage) stage3(buf, c + 3);
    f32x4 a = (f32x4){0.f, 0.f, 0.f, 0.f};
#pragma unroll
    for (int f = 0; f < 8; ++f)
      a = __builtin_amdgcn_mfma_f32_16x16x32_f16(af3[f], bf3[f], a, 0, 0, 0);
#pragma unroll
    for (int q = 0; q < 4; ++q) {
      const int row = bm + wid * 16 + lkg * 4 + q;
      float v = a[q] * INV_ACT_SCALE + bv;
      size_t grow = (size_t)row;
      float* dst = (col < 512)
                       ? (out + grow * 512 + col)
                       : (out + (size_t)nTotal * 512 + grow * 512 + (col - 512));
      __builtin_nontemporal_store(v, dst);
    }
  };

  body3(0, 0, true);
  body3(1, 0, true);
  for (int c = 2; c <= 60; ++c) body3(c, 9, true);
  body3(61, 9, false);
  body3(62, 8, false);
  body3(63, 0, false);
}

// ---------------- launch ----------------
extern "C" void kernel_launch(void* const* d_in, const int* in_sizes, int n_in,
                              void* d_out, int out_size, void* d_ws, size_t ws_size,
                              hipStream_t stream)
{
  const float* x   = (const float*)d_in[0];
  const float* emb = (const float*)d_in[1];
  const float* W1  = (const float*)d_in[2];
  const float* b1  = (const float*)d_in[3];
  const float* W2  = (const float*)d_in[4];
  const float* b2  = (const float*)d_in[5];
  const float* W3  = (const float*)d_in[6];
  const float* b3  = (const float*)d_in[7];
  float* out = (float*)d_out;

  const int NPTS = in_sizes[0] / 3;  // 262144

  f16* Wf1 = (f16*)d_ws;                 // 128*256 frag-ordered
  f16* Wf2 = Wf1 + 128 * 256;            // 256*256 frag-ordered
  f16* Wt3 = Wf2 + 256 * 256;            // 256*1024 transposed [N][K]

  prep_w1f<<<(128 * 256 + 255) / 256, 256, 0, stream>>>(W1, Wf1);
  prep_w2f<<<(256 * 256 + 255) / 256, 256, 0, stream>>>(W2, Wf2);
  prep_w<256, 1024><<<(256 * 1024 + 255) / 256, 256, 0, stream>>>(W3, Wt3);

  mega_kernel<<<NPTS / 128, 512, 0, stream>>>(x, emb, Wf1, b1, Wf2, b2,
                                              Wt3, b3, out, NPTS);
}

// Round 18
// 767.618 us; speedup vs baseline: 1.4435x; 1.2687x over previous
//
#include <hip/hip_runtime.h>
#include <cstdint>

#pragma STDC FP_CONTRACT OFF

// ---------------------------------------------------------------------------
// GridCLIP forward: hash-grid encode (16 levels x 8) -> MLP 128->256->256->1024
// Round 18: revert to R15 (best, 834us) + one contained ph3 fix:
//   - W3 streamed as 32-col chunks (16KB) in a 3-deep ring living in H1
//     (dead after ph2; As2 deleted; LDS 156->132KB)
//   - iterations 64->32 (half the barriers), per-iter ops 2 loads + 8 stores
//   - counted waits re-derived for the certify-2-back handshake: steady
//     vmcnt(18), tail vmcnt(16); post-ph2 stage chunks 0-2 + __syncthreads
//   - NT stores on out (protect W3's L2 residency)
// Encode = R15-verbatim (barriered variant — measured faster than the
// "de-serialized" R16 one). All math identical -> bit-identical output
// (canary absmax 4.768372e-07).
// ---------------------------------------------------------------------------

typedef _Float16 f16;
typedef __attribute__((ext_vector_type(8))) _Float16 f16x8;
typedef __attribute__((ext_vector_type(4))) float f32x4;

#define ACT_SCALE 4096.0f
#define INV_ACT_SCALE (1.0f / 4096.0f)

__device__ __forceinline__ void gld16(const void* g, void* l) {
  __builtin_amdgcn_global_load_lds(
      (const __attribute__((address_space(1))) void*)(uintptr_t)g,
      (__attribute__((address_space(3))) void*)(uint32_t)(uintptr_t)l,
      16, 0, 0);
}

// ---------------- grid encode (R15-verbatim: XLA chain, barriered) ---------
__global__ __launch_bounds__(256) void grid_encode_kernel(
    const float* __restrict__ x, const float* __restrict__ emb,
    f16* __restrict__ gh, int p0, int npts)
{
#pragma clang fp contract(off)
  int g = blockIdx.x * blockDim.x + threadIdx.x;
  if (g >= npts * 16) return;
  int pl = g >> 4;
  int l  = g & 15;
  int p  = p0 + pl;

  float x0 = x[3 * p + 0];
  float x1 = x[3 * p + 1];
  float x2 = x[3 * p + 2];

  float t0 = (x0 + 10.0f) * 0.05f;
  float t1 = (x1 + 10.0f) * 0.05f;
  float t2 = (x2 + 10.0f) * 0.05f;
  asm volatile("" : "+v"(t0), "+v"(t1), "+v"(t2));
  float u0 = (t0 + 1.0f) * 0.5f;
  float u1 = (t1 + 1.0f) * 0.5f;
  float u2 = (t2 + 1.0f) * 0.5f;
  asm volatile("" : "+v"(u0), "+v"(u1), "+v"(u2));

  float scale = (float)((16 << l) - 1);
  float pos0 = u0 * scale + 0.5f;
  float pos1 = u1 * scale + 0.5f;
  float pos2 = u2 * scale + 0.5f;

  float fb0 = floorf(pos0), fb1 = floorf(pos1), fb2 = floorf(pos2);
  float f0 = pos0 - fb0;
  float f1 = pos1 - fb1;
  float f2 = pos2 - fb2;
  uint32_t px = (uint32_t)fb0, py = (uint32_t)fb1, pz = (uint32_t)fb2;

  uint32_t mask = (l < 3) ? ((4096u << (3 * l)) - 1u) : 2097151u;
  uint32_t off;
  if (l == 0)      off = 0u;
  else if (l == 1) off = 4096u;
  else if (l == 2) off = 36864u;
  else             off = 299008u + (uint32_t)(l - 3) * 2097152u;

  float wx[2] = {1.0f - f0, f0};
  float wy[2] = {1.0f - f1, f1};
  float wz[2] = {1.0f - f2, f2};

  float acc[8];
#pragma unroll
  for (int j = 0; j < 8; ++j) acc[j] = 0.0f;

#pragma unroll
  for (int c = 0; c < 8; ++c) {
    uint32_t cx = px + (uint32_t)(c & 1);
    uint32_t cy = py + (uint32_t)((c >> 1) & 1);
    uint32_t cz = pz + (uint32_t)((c >> 2) & 1);
    float w = wx[c & 1] * wy[(c >> 1) & 1] * wz[(c >> 2) & 1];
    uint32_t h = cx ^ (cy * 2654435761u) ^ (cz * 805459861u);
    uint32_t idx = (h & mask) + off;
    const float4* e = (const float4*)(emb + (size_t)idx * 8);
    float4 e0 = e[0];
    float4 e1 = e[1];
    float m0 = w * e0.x, m1 = w * e0.y, m2 = w * e0.z, m3 = w * e0.w;
    float m4 = w * e1.x, m5 = w * e1.y, m6 = w * e1.z, m7 = w * e1.w;
    asm volatile("" : "+v"(m0), "+v"(m1), "+v"(m2), "+v"(m3),
                      "+v"(m4), "+v"(m5), "+v"(m6), "+v"(m7));
    acc[0] += m0; acc[1] += m1; acc[2] += m2; acc[3] += m3;
    acc[4] += m4; acc[5] += m5; acc[6] += m6; acc[7] += m7;
  }

  f16x8 o;
#pragma unroll
  for (int j = 0; j < 8; ++j) o[j] = (f16)(acc[j] * ACT_SCALE);
  *(f16x8*)&gh[(size_t)pl * 128 + l * 8] = o;
}

// ---------------- weight preps ---------------------------------------------
template <int K, int N>
__global__ __launch_bounds__(256) void prep_w(
    const float* __restrict__ W, f16* __restrict__ Wt)
{
  int i = blockIdx.x * 256 + threadIdx.x;
  if (i >= N * K) return;
  int n = i / K, k = i - n * K;
  Wt[i] = (f16)W[(size_t)k * N + n];
}

__global__ __launch_bounds__(256) void prep_w1f(
    const float* __restrict__ W1, f16* __restrict__ Wf1)
{
  int i = blockIdx.x * 256 + threadIdx.x;
  if (i >= 128 * 256) return;
  int e  = i & 7;
  int lr = (i >> 3) & 15;
  int kg = (i >> 7) & 15;
  int q  = i >> 11;
  int n = q * 16 + lr;
  int k = kg * 8 + e;
  Wf1[i] = (f16)W1[(size_t)k * 256 + n];
}

__global__ __launch_bounds__(256) void prep_w2f(
    const float* __restrict__ W2, f16* __restrict__ Wf2)
{
  int i = blockIdx.x * 256 + threadIdx.x;
  if (i >= 256 * 256) return;
  int e  = i & 7;
  int lr = (i >> 3) & 15;
  int kg = (i >> 7) & 31;
  int q  = i >> 12;
  int n = q * 16 + lr;
  int k = kg * 8 + e;
  Wf2[i] = (f16)W2[(size_t)k * 256 + n];
}

// ---------------- fused MLP ------------------------------------------------
__global__ __launch_bounds__(512) void fused_mlp(
    const f16* __restrict__ gh, const f16* __restrict__ Wf1,
    const float* __restrict__ b1, const f16* __restrict__ Wf2,
    const float* __restrict__ b2, const f16* __restrict__ Wt3,
    const float* __restrict__ b3, float* __restrict__ out,
    int rowBase, int nTotal)
{
  __shared__ alignas(16) f16 H1[128 * 256];  // 64KB h1; W3 ring (3x16KB) in ph3
  __shared__ alignas(16) f16 H2[128 * 256];  // 64KB h2 (gh during ph1)
  __shared__ float B3s[1024];                // 4KB b3 cache

  const int tid  = threadIdx.x;
  const int lane = tid & 63;
  const int wid  = tid >> 6;      // 0..7
  const int bm   = blockIdx.x * 128;
  const int lr   = lane & 15;
  const int lkg  = lane >> 4;     // 0..3

  // W3 32-col chunk staging: 1024 granules, 2 gld16/thread, ring in H1
  auto stage3 = [&](int buf, int c) {
#pragma unroll
    for (int s = 0; s < 2; ++s) {
      const int g   = tid + s * 512;
      const int row = g >> 5;                       // col-in-chunk 0..31
      const int sg  = g & 31;
      const int gs  = (sg & 24) | ((sg ^ row) & 7);
      gld16(&Wt3[(size_t)(c * 32 + row) * 256 + gs * 8],
            &H1[buf * 8192 + g * 8]);
    }
  };

  // ---- prologue: gh tile (32KB into H2) + b3 cache
#pragma unroll
  for (int s = 0; s < 4; ++s) {
    const int g   = tid + s * 512;
    const int row = g >> 4;
    const int sg  = g & 15;
    const int gs  = (sg & 8) | ((sg ^ row) & 7);
    gld16(&gh[(size_t)(bm + row) * 128 + gs * 8], &H2[g * 8]);
  }
  B3s[tid] = b3[tid];
  B3s[tid + 512] = b3[tid + 512];
  __syncthreads();

  // ===== phase 1: h1 = relu(gh @ W1 + b1*S) =====
  {
    const int rowg = wid >> 2, colg = wid & 3;
    f16x8 bf1[4][4];
#pragma unroll
    for (int j = 0; j < 4; ++j)
#pragma unroll
      for (int f = 0; f < 4; ++f)
        bf1[j][f] = *(const f16x8*)&Wf1[(((colg * 4 + j) * 16 + f * 4 + lkg) * 16 + lr) * 8];

    f32x4 acc[4][4];
#pragma unroll
    for (int i = 0; i < 4; ++i)
#pragma unroll
      for (int j = 0; j < 4; ++j) acc[i][j] = (f32x4){0.f, 0.f, 0.f, 0.f};

#pragma unroll
    for (int f = 0; f < 4; ++f) {
      f16x8 af[4];
#pragma unroll
      for (int i = 0; i < 4; ++i) {
        const int r  = rowg * 64 + i * 16 + lr;
        const int kg = f * 4 + lkg;
        const int gs = (kg & 8) | ((kg ^ r) & 7);
        af[i] = *(const f16x8*)&H2[r * 128 + gs * 8];
      }
#pragma unroll
      for (int i = 0; i < 4; ++i)
#pragma unroll
        for (int j = 0; j < 4; ++j)
          acc[i][j] = __builtin_amdgcn_mfma_f32_16x16x32_f16(
              af[i], bf1[j][f], acc[i][j], 0, 0, 0);
    }

#pragma unroll
    for (int i = 0; i < 4; ++i)
#pragma unroll
      for (int j = 0; j < 4; ++j) {
        const int col = colg * 64 + j * 16 + lr;
        const float bv = b1[col];
        const int kg = col >> 3, e = col & 7;
#pragma unroll
        for (int q = 0; q < 4; ++q) {
          const int row = rowg * 64 + i * 16 + lkg * 4 + q;
          const int kgs = (kg & 24) | ((kg ^ row) & 7);
          float v = fmaxf(acc[i][j][q] + bv * ACT_SCALE, 0.0f);
          H1[row * 256 + kgs * 8 + e] = (f16)v;
        }
      }
  }
  __syncthreads();

  // ===== phase 2: h2 = relu(h1 @ W2 + b2*S) =====
  {
    const int rowg = wid >> 2, colg = wid & 3;
    f16x8 bf2[4][8];
#pragma unroll
    for (int j = 0; j < 4; ++j)
#pragma unroll
      for (int f = 0; f < 8; ++f)
        bf2[j][f] = *(const f16x8*)&Wf2[(((colg * 4 + j) * 32 + f * 4 + lkg) * 16 + lr) * 8];

    f32x4 acc[4][4];
#pragma unroll
    for (int i = 0; i < 4; ++i)
#pragma unroll
      for (int j = 0; j < 4; ++j) acc[i][j] = (f32x4){0.f, 0.f, 0.f, 0.f};

#pragma unroll
    for (int f = 0; f < 8; ++f) {
      f16x8 af[4];
#pragma unroll
      for (int i = 0; i < 4; ++i) {
        const int r   = rowg * 64 + i * 16 + lr;
        const int kg  = f * 4 + lkg;
        const int kgs = (kg & 24) | ((kg ^ r) & 7);
        af[i] = *(const f16x8*)&H1[r * 256 + kgs * 8];
      }
#pragma unroll
      for (int i = 0; i < 4; ++i)
#pragma unroll
        for (int j = 0; j < 4; ++j)
          acc[i][j] = __builtin_amdgcn_mfma_f32_16x16x32_f16(
              af[i], bf2[j][f], acc[i][j], 0, 0, 0);
    }

#pragma unroll
    for (int i = 0; i < 4; ++i)
#pragma unroll
      for (int j = 0; j < 4; ++j) {
        const int col = colg * 64 + j * 16 + lr;
        const float bv = b2[col];
        const int kg = col >> 3, e = col & 7;
#pragma unroll
        for (int q = 0; q < 4; ++q) {
          const int row = rowg * 64 + i * 16 + lkg * 4 + q;
          const int kgs = (kg & 24) | ((kg ^ row) & 7);
          float v = fmaxf(acc[i][j][q] + bv * ACT_SCALE, 0.0f);
          H2[row * 256 + kgs * 8 + e] = (f16)v;
        }
      }
  }
  __syncthreads();  // h2 visible; H1 now dead -> becomes the W3 ring

  // ===== phase 3: out = h2 @ W3 + b3 — 32 chunks of 32 cols, ring-3 in H1 ==
  f16x8 af3[8];
#pragma unroll
  for (int f = 0; f < 8; ++f) {
    const int r   = wid * 16 + lr;
    const int kg  = f * 4 + lkg;
    const int kgs = (kg & 24) | ((kg ^ r) & 7);
    af3[f] = *(const f16x8*)&H2[r * 256 + kgs * 8];
  }

  stage3(0, 0);
  stage3(1, 1);
  stage3(2, 2);
  __syncthreads();  // full drain: chunks 0-2 certified + published

  // per wave per iter: 2 gld16 + 8 stores. Wait at iter c certifies this
  // wave's stage(c+1) loads (issued iter c-2): ops after = st8 + (2+8) = 18.
  // The iter-c barrier publishes; read of chunk c+1 at iter c+1 is safe.
  // Tail (no stage at c>=29): iter30 certifies stage(31)@i28: 8+8=16.
  auto body3 = [&](int c, int wmode, bool dostage) {
    if (wmode == 18) {
      asm volatile("s_waitcnt vmcnt(18)" ::: "memory");
      __builtin_amdgcn_sched_barrier(0);
    } else if (wmode == 16) {
      asm volatile("s_waitcnt vmcnt(16)" ::: "memory");
      __builtin_amdgcn_sched_barrier(0);
    }
    const int buf = c % 3;
    f16x8 bf3[2][8];
#pragma unroll
    for (int cg = 0; cg < 2; ++cg)
#pragma unroll
      for (int f = 0; f < 8; ++f) {
        const int n   = cg * 16 + lr;
        const int kg  = f * 4 + lkg;
        const int kgs = (kg & 24) | ((kg ^ n) & 7);
        bf3[cg][f] = *(const f16x8*)&H1[buf * 8192 + (n * 32 + kgs) * 8];
      }
    asm volatile("s_waitcnt lgkmcnt(0)" ::: "memory");
    __builtin_amdgcn_sched_barrier(0);
    __builtin_amdgcn_s_barrier();
    __builtin_amdgcn_sched_barrier(0);
    if (dostage) stage3(buf, c + 3);
    f32x4 a[2];
#pragma unroll
    for (int cg = 0; cg < 2; ++cg) {
      a[cg] = (f32x4){0.f, 0.f, 0.f, 0.f};
#pragma unroll
      for (int f = 0; f < 8; ++f)
        a[cg] = __builtin_amdgcn_mfma_f32_16x16x32_f16(af3[f], bf3[cg][f],
                                                       a[cg], 0, 0, 0);
    }
#pragma unroll
    for (int cg = 0; cg < 2; ++cg) {
      const int col = c * 32 + cg * 16 + lr;
      const float bv = B3s[col];
#pragma unroll
      for (int q = 0; q < 4; ++q) {
        const int row = bm + wid * 16 + lkg * 4 + q;
        float v = a[cg][q] * INV_ACT_SCALE + bv;
        size_t grow = (size_t)(rowBase + row);
        float* dst = (col < 512)
                         ? (out + grow * 512 + col)
                         : (out + (size_t)nTotal * 512 + grow * 512 + (col - 512));
        __builtin_nontemporal_store(v, dst);
      }
    }
  };

  body3(0, 18, true);
  body3(1, 18, true);
  for (int c = 2; c <= 28; ++c) body3(c, 18, true);
  body3(29, 18, false);
  body3(30, 16, false);
  body3(31, 16, false);
}

// ---------------- launch ----------------
extern "C" void kernel_launch(void* const* d_in, const int* in_sizes, int n_in,
                              void* d_out, int out_size, void* d_ws, size_t ws_size,
                              hipStream_t stream)
{
  const float* x   = (const float*)d_in[0];
  const float* emb = (const float*)d_in[1];
  const float* W1  = (const float*)d_in[2];
  const float* b1  = (const float*)d_in[3];
  const float* W2  = (const float*)d_in[4];
  const float* b2  = (const float*)d_in[5];
  const float* W3  = (const float*)d_in[6];
  const float* b3  = (const float*)d_in[7];
  float* out = (float*)d_out;

  const int NPTS = in_sizes[0] / 3;  // 262144

  f16* Wf1 = (f16*)d_ws;                 // 128*256 frag-ordered
  f16* Wf2 = Wf1 + 128 * 256;            // 256*256 frag-ordered
  f16* Wt3 = Wf2 + 256 * 256;            // 256*1024 transposed [N][K]
  f16* gh0 = Wt3 + 256 * 1024;
  const size_t wtBytes = (size_t)(128 * 256 + 256 * 256 + 256 * 1024) * sizeof(f16);

  long long cmax = (long long)((ws_size - wtBytes) / 256);
  int C = (int)((cmax / 128) * 128);
  if (C > NPTS) C = NPTS;
  if (C < 128) C = 128;

  prep_w1f<<<(128 * 256 + 255) / 256, 256, 0, stream>>>(W1, Wf1);
  prep_w2f<<<(256 * 256 + 255) / 256, 256, 0, stream>>>(W2, Wf2);
  prep_w<256, 1024><<<(256 * 1024 + 255) / 256, 256, 0, stream>>>(W3, Wt3);

  for (int p0 = 0; p0 < NPTS; p0 += C) {
    int cur = (NPTS - p0 < C) ? (NPTS - p0) : C;

    int nthr = cur * 16;
    grid_encode_kernel<<<(nthr + 255) / 256, 256, 0, stream>>>(x, emb, gh0, p0, cur);

    fused_mlp<<<cur / 128, 512, 0, stream>>>(gh0, Wf1, b1, Wf2, b2, Wt3, b3,
                                             out, p0, NPTS);
  }
}